// Round 6
// baseline (746.504 us; speedup 1.0000x reference)
//
#include <hip/hip_runtime.h>
#include <hip/hip_bf16.h>
#include <math.h>

// Problem dims (fixed by reference setup_inputs)
#define D_IN   1024
#define D_HID  4096
#define M_TOK  16384   // 4 * 4096 tokens

typedef int v4i __attribute__((ext_vector_type(4)));
typedef _Float16 f16x8 __attribute__((ext_vector_type(8)));

typedef __attribute__((address_space(3))) unsigned int lds_u32;
typedef const __attribute__((address_space(1))) unsigned int glb_u32;

// async global->LDS, 16B per lane, wave-uniform LDS base + lane*16
__device__ inline void gload_lds16(const signed char* g, signed char* l) {
    __builtin_amdgcn_global_load_lds((glb_u32*)g, (lds_u32*)l, 16, 0, 0);
}

// Branchless erf, Abramowitz-Stegun 7.1.26, |eps| <= 1.5e-7 (<< fp16-h rounding).
__device__ inline float fast_erf(float x) {
    float ax = fabsf(x);
    float t = __builtin_amdgcn_rcpf(fmaf(0.3275911f, ax, 1.0f));
    float y = t * (0.254829592f +
              t * (-0.284496736f +
              t * (1.421413741f +
              t * (-1.453152027f +
              t * 1.061405429f))));
    float e = __expf(-ax * ax);          // native v_exp path
    float r = fmaf(-y, e, 1.0f);
    return copysignf(r, x);
}

// ---------------- workspace layout (bytes) ----------------
#define OFF_SLOTS  ((size_t)0)                                   // 8 x u32 atomic slots
#define OFF_SCAL   ((size_t)64)                                  // 16 x f32 scalars
#define OFF_ISCAL  ((size_t)128)                                 // 8 x i32
#define OFF_XQ     ((size_t)256)                                 // 16M  int8
#define OFF_W1Q    (OFF_XQ  + (size_t)M_TOK * D_IN)              // 4M   int8
#define OFF_W2Q    (OFF_W1Q + (size_t)D_HID * D_IN)              // 4M   int8
#define OFF_RS1    (OFF_W2Q + (size_t)D_IN * D_HID)              // 16K  i32
#define OFF_RS2    (OFF_RS1 + (size_t)D_HID * 4)                 // 4K   i32
#define OFF_H      (OFF_RS2 + (size_t)D_IN * 4 + 128)            // 128M fp16
#define OFF_HQ     (OFF_H   + (size_t)M_TOK * D_HID * 2)         // 64M  int8
// total ~226.5 MB
// NOTE: the RS1/RS2 regions double as the reduction-partials buffer for
// k_reduce_all/k_scales_all (kernels 1-2); k_quant_all (kernel 3) then
// overwrites them with the real row sums. Strictly ordered by stream.

// slots: [4] h min(enc) [5] h max(enc)   (only gemm1 atomics use slots now)
// scal:  [0] sx1 [1] zx1f [2] sw1 [3] sw2 [4] s1=sx1*sw1
// iscal: [0] zx1

__device__ inline unsigned enc_f(float f) {
    unsigned u = __float_as_uint(f);
    return (u & 0x80000000u) ? ~u : (u | 0x80000000u);
}
__device__ inline float dec_f(unsigned u) {
    return __uint_as_float((u & 0x80000000u) ? (u ^ 0x80000000u) : ~u);
}

// ---- fused stage-1 reductions: x min/max + |W1|max + |W2|max, deterministic partials
__global__ void k_reduce_all(const float4* __restrict__ x,
                             const float4* __restrict__ w1,
                             const float4* __restrict__ w2,
                             float* __restrict__ pxmin, float* __restrict__ pxmax,
                             float* __restrict__ pw1, float* __restrict__ pw2) {
    __shared__ float red[8];
    const int b = blockIdx.x;
    const int wave = threadIdx.x >> 6, lane = threadIdx.x & 63;
    if (b < 1024) {
        float vmin = 3.4e38f, vmax = -3.4e38f;
        for (int i = b * 256 + threadIdx.x; i < M_TOK * D_IN / 4; i += 1024 * 256) {
            float4 v = x[i];
            vmin = fminf(vmin, fminf(fminf(v.x, v.y), fminf(v.z, v.w)));
            vmax = fmaxf(vmax, fmaxf(fmaxf(v.x, v.y), fmaxf(v.z, v.w)));
        }
        for (int off = 32; off > 0; off >>= 1) {
            vmin = fminf(vmin, __shfl_down(vmin, off));
            vmax = fmaxf(vmax, __shfl_down(vmax, off));
        }
        if (lane == 0) { red[wave] = vmin; red[4 + wave] = vmax; }
        __syncthreads();
        if (threadIdx.x == 0) {
            pxmin[b] = fminf(fminf(red[0], red[1]), fminf(red[2], red[3]));
            pxmax[b] = fmaxf(fmaxf(red[4], red[5]), fmaxf(red[6], red[7]));
        }
    } else {
        const float4* w = (b < 1280) ? w1 : w2;
        const int bb = (b < 1280) ? b - 1024 : b - 1280;
        float vmax = 0.0f;
        for (int i = bb * 256 + threadIdx.x; i < D_HID * D_IN / 4; i += 256 * 256) {
            float4 v = w[i];
            vmax = fmaxf(vmax, fmaxf(fmaxf(fabsf(v.x), fabsf(v.y)), fmaxf(fabsf(v.z), fabsf(v.w))));
        }
        for (int off = 32; off > 0; off >>= 1)
            vmax = fmaxf(vmax, __shfl_down(vmax, off));
        if (lane == 0) red[wave] = vmax;
        __syncthreads();
        if (threadIdx.x == 0) {
            float bm = fmaxf(fmaxf(red[0], red[1]), fmaxf(red[2], red[3]));
            if (b < 1280) pw1[bb] = bm; else pw2[bb] = bm;
        }
    }
}

// single wave: reduce partials -> all stage-1 scales + init gemm1 atomic slots
__global__ void k_scales_all(const float* __restrict__ pxmin, const float* __restrict__ pxmax,
                             const float* __restrict__ pw1, const float* __restrict__ pw2,
                             float* scal, int* iscal, unsigned* slots) {
    const int lane = threadIdx.x;
    float vmin = 3.4e38f, vmax = -3.4e38f;
    for (int i = lane; i < 1024; i += 64) {
        vmin = fminf(vmin, pxmin[i]);
        vmax = fmaxf(vmax, pxmax[i]);
    }
    float w1m = 0.0f, w2m = 0.0f;
    for (int i = lane; i < 256; i += 64) {
        w1m = fmaxf(w1m, pw1[i]);
        w2m = fmaxf(w2m, pw2[i]);
    }
    for (int off = 32; off > 0; off >>= 1) {
        vmin = fminf(vmin, __shfl_down(vmin, off));
        vmax = fmaxf(vmax, __shfl_down(vmax, off));
        w1m  = fmaxf(w1m,  __shfl_down(w1m, off));
        w2m  = fmaxf(w2m,  __shfl_down(w2m, off));
    }
    if (lane == 0) {
        float sx = fmaxf((vmax - vmin) / 255.0f, 1e-8f);
        float zx = rintf(-vmin / sx) - 128.0f;
        zx = fminf(fmaxf(zx, -128.0f), 127.0f);
        float sw1 = fmaxf(w1m / 127.0f, 1e-8f);
        float sw2 = fmaxf(w2m / 127.0f, 1e-8f);
        scal[0] = sx; scal[1] = zx; scal[2] = sw1; scal[3] = sw2; scal[4] = sx * sw1;
        iscal[0] = (int)zx;
        slots[4] = 0xFFFFFFFFu;   // h min (enc)
        slots[5] = 0u;            // h max (enc)
    }
}

// ---- fused stage-1 quantization: x (blocks 0..2047), W1 rows (2048..6143), W2 rows (6144..7167)
__global__ void k_quant_all(const float4* __restrict__ x, int* __restrict__ xq,
                            const float* __restrict__ W1, signed char* __restrict__ w1q,
                            int* __restrict__ rs1,
                            const float* __restrict__ W2, signed char* __restrict__ w2q,
                            int* __restrict__ rs2,
                            const float* __restrict__ scal) {
    __shared__ int red[4];
    const int b = blockIdx.x;
    if (b < 2048) {
        float s = scal[0], zp = scal[1];
        for (int i = b * 256 + threadIdx.x; i < M_TOK * D_IN / 4; i += 2048 * 256) {
            float4 v = x[i];
            int a0 = (int)fminf(fmaxf(rintf(v.x / s) + zp, -128.0f), 127.0f);
            int a1 = (int)fminf(fmaxf(rintf(v.y / s) + zp, -128.0f), 127.0f);
            int a2 = (int)fminf(fmaxf(rintf(v.z / s) + zp, -128.0f), 127.0f);
            int a3 = (int)fminf(fmaxf(rintf(v.w / s) + zp, -128.0f), 127.0f);
            xq[i] = (a0 & 255) | ((a1 & 255) << 8) | ((a2 & 255) << 16) | ((a3 & 255) << 24);
        }
        return;
    }
    const int isW1 = (b < 2048 + 4096);
    const int row = isW1 ? (b - 2048) : (b - 6144);
    const int K = isW1 ? D_IN : D_HID;
    const float s = isW1 ? scal[2] : scal[3];
    const float* W = isW1 ? W1 : W2;
    signed char* Wq = isW1 ? w1q : w2q;
    int* rsum = isW1 ? rs1 : rs2;

    const float4* Wr = (const float4*)(W + (size_t)row * K);
    int* out = (int*)(Wq + (size_t)row * K);
    int mysum = 0;
    for (int i = threadIdx.x; i < K / 4; i += 256) {
        float4 v = Wr[i];
        int a0 = (int)fminf(fmaxf(rintf(v.x / s), -127.0f), 127.0f);
        int a1 = (int)fminf(fmaxf(rintf(v.y / s), -127.0f), 127.0f);
        int a2 = (int)fminf(fmaxf(rintf(v.z / s), -127.0f), 127.0f);
        int a3 = (int)fminf(fmaxf(rintf(v.w / s), -127.0f), 127.0f);
        mysum += a0 + a1 + a2 + a3;
        out[i] = (a0 & 255) | ((a1 & 255) << 8) | ((a2 & 255) << 16) | ((a3 & 255) << 24);
    }
    for (int off = 32; off > 0; off >>= 1)
        mysum += __shfl_down(mysum, off);
    const int wave = threadIdx.x >> 6, lane = threadIdx.x & 63;
    if (lane == 0) red[wave] = mysum;
    __syncthreads();
    if (threadIdx.x == 0) rsum[row] = red[0] + red[1] + red[2] + red[3];
}

// h quant: scales decoded inline from slots (k_scales2 kernel eliminated)
__global__ void k_quant_h(const f16x8* __restrict__ H, int2* __restrict__ Hq, int n8,
                          const unsigned* __restrict__ slots) {
    float amin = dec_f(slots[4]), amax = dec_f(slots[5]);
    float s = fmaxf((amax - amin) / 255.0f, 1e-8f);
    float zp = rintf(-amin / s) - 128.0f;
    zp = fminf(fmaxf(zp, -128.0f), 127.0f);
    for (int i = blockIdx.x * blockDim.x + threadIdx.x; i < n8; i += gridDim.x * blockDim.x) {
        f16x8 v = H[i];
        int q[8];
#pragma unroll
        for (int j = 0; j < 8; j++)
            q[j] = ((int)fminf(fmaxf(rintf((float)v[j] / s) + zp, -128.0f), 127.0f)) & 255;
        int lo = q[0] | (q[1] << 8) | (q[2] << 16) | (q[3] << 24);
        int hi = q[4] | (q[5] << 8) | (q[6] << 16) | (q[7] << 24);
        Hq[i] = make_int2(lo, hi);
    }
}

// ---------------- int8 MFMA GEMM mainloop, 256x128 tile ----------------
// C[m][n] = sum_k A[m][k] * B[n][k]   (both row-major, K contiguous)
// BM=256, BN=128, BK=64, 256 threads = 2x2 wave grid, per-wave output 128x64
// (8x4 of 16x16x64 tiles => 32 MFMA per wave per K-tile, 12 ds_read_b128).
//
// R6: DOUBLE-buffered LDS (2 x 24KB = 48KB -> 3 blocks/CU via
// __launch_bounds__(256,3)), stage-early/wait-late counted vmcnt:
//   per tile t: stage(t+1) -> other buf; s_waitcnt vmcnt(6); s_barrier;
//               compute(buf t); s_barrier.
// vmcnt ledger: at the wait, outstanding = tile t's 6 (issued at t-1) +
// tile t+1's 6 (just issued) = 12 -> vmcnt(6) drains exactly tile t.
// Never 0 mid-loop; tail (t=KT-1, nothing staged) -> vmcnt(0).
// Issue-to-wait distance = 1 full tile (>~3000 cy) >> ~900 cy HBM latency.
// Buffer safety: stage(t+1) writes buf((t+1)&1), last read by compute(t-1)
// (same parity); those ds_reads completed (lgkmcnt before their MFMAs)
// before t-1's trailing barrier, which all waves passed before any wave
// issues iteration t's stage. 3 blocks/CU (vs 2) is the point: 3 waves/SIMD
// of MFMA demand (~1960 cy/tile) to fill the serial stage/barrier sections
// (R4: 2 waves, MfmaUtil 23%; R5's intra-block phase split regressed - with
// only 4 waves/block there is no role diversity to arbitrate, so overlap
// must come from more independent blocks).
// LDS chunk swizzle (verified 0-conflict): LDS chunk c of row r holds global
// chunk c ^ ((r>>1)&3); writer gc = (l&3) ^ ((l>>3)&3), reader f = lq ^ ((lm>>1)&3).
__device__ inline void int8_mainloop256(const signed char* __restrict__ A,
                                        const signed char* __restrict__ B,
                                        int K, int m0, int n0,
                                        signed char* Ls, v4i (&acc)[8][4]) {
    const int tid = threadIdx.x;
    const int l = tid & 63, w = tid >> 6;
    const int lm = l & 15, lq = l >> 4;
    const int wmi = w >> 1, wni = w & 1;

    const int gc16 = ((l & 3) ^ ((l >> 3) & 3)) << 4;   // swizzled global chunk
    const int srow = (w << 4) + (l >> 2);               // rows 0..63 (+q*64)
    const signed char* gA = A + (long)(m0 + srow) * K + gc16;
    const signed char* gB = B + (long)(n0 + srow) * K + gc16;
    const long rstep = (long)K << 6;                    // 64 rows
    signed char* lA = Ls + (w << 10) + (l << 4);
    signed char* lB = Ls + 16384 + (w << 10) + (l << 4);

    const int f16off = (lq ^ ((lm >> 1) & 3)) << 4;
    const int aoff = ((wmi << 7) + lm) * 64 + f16off;
    const int boff = 16384 + ((wni << 6) + lm) * 64 + f16off;

    const int KT = K >> 6;   // 16 for K=1024, 64 for K=4096

    auto stage = [&](int bufoff, int kt) {
        const signed char* a = gA + ((long)kt << 6);
        const signed char* b = gB + ((long)kt << 6);
        gload_lds16(a,             lA + bufoff);
        gload_lds16(a + rstep,     lA + bufoff + 4096);
        gload_lds16(a + 2 * rstep, lA + bufoff + 8192);
        gload_lds16(a + 3 * rstep, lA + bufoff + 12288);
        gload_lds16(b,             lB + bufoff);
        gload_lds16(b + rstep,     lB + bufoff + 4096);
    };

    auto compute = [&](int bufoff) {
        v4i av[8], bv[4];
#pragma unroll
        for (int j = 0; j < 4; ++j)
            bv[j] = *(const v4i*)&Ls[bufoff + boff + j * 1024];
#pragma unroll
        for (int i = 0; i < 8; ++i)
            av[i] = *(const v4i*)&Ls[bufoff + aoff + i * 1024];
        __builtin_amdgcn_s_setprio(1);
#pragma unroll
        for (int i = 0; i < 8; ++i)
#pragma unroll
            for (int j = 0; j < 4; ++j)
                acc[i][j] = __builtin_amdgcn_mfma_i32_16x16x64_i8(av[i], bv[j], acc[i][j], 0, 0, 0);
        __builtin_amdgcn_s_setprio(0);
    };

    // prologue: tile 0 -> buffer 0
    stage(0, 0);

    for (int t = 0; t < KT; ++t) {
        const int cur = (t & 1) * 24576;
        if (t + 1 < KT) {
            stage(24576 - cur, t + 1);   // overwrites buffer consumed at t-1
            asm volatile("s_waitcnt vmcnt(6)\n\ts_barrier" ::: "memory");
        } else {
            asm volatile("s_waitcnt vmcnt(0)\n\ts_barrier" ::: "memory");
        }
        compute(cur);
        asm volatile("s_barrier" ::: "memory");
    }
}

__global__ __launch_bounds__(256, 3) void k_gemm1(const signed char* __restrict__ Aq,
                                                  const signed char* __restrict__ Bq,
                                                  _Float16* __restrict__ H,
                                                  const float* __restrict__ scal,
                                                  const int* __restrict__ iscal,
                                                  const int* __restrict__ rsum,
                                                  const float* __restrict__ bias,
                                                  unsigned* slots) {
    __shared__ __align__(16) signed char Ls[2 * 24576];   // 48KB -> 3 blocks/CU
    __shared__ float red[8];
    const int nb = D_HID / 128;
    const int m0 = (blockIdx.x / nb) * 256, n0 = (blockIdx.x % nb) * 128;
    v4i acc[8][4];
    v4i zero = {0, 0, 0, 0};
#pragma unroll
    for (int i = 0; i < 8; i++)
#pragma unroll
        for (int j = 0; j < 4; j++) acc[i][j] = zero;
    int8_mainloop256(Aq, Bq, D_IN, m0, n0, Ls, acc);

    const int tid = threadIdx.x, l = tid & 63, w = tid >> 6;
    const int lm = l & 15, lq = l >> 4;
    const int wmi = w >> 1, wni = w & 1;
    float s1 = scal[4];
    int zx = iscal[0];
    float lmin = 3.4e38f, lmax = -3.4e38f;
    // direct store epilogue (R2-verified): 48KB LDS can't hold the 64KB
    // H-tile; R2-vs-R4 showed the LDS-coalesced store bought only ~2us on
    // gemm1's critical path, and HBM write amplification is not limiting.
#pragma unroll
    for (int j = 0; j < 4; j++) {
        int n = n0 + (wni << 6) + j * 16 + lm;
        int rsn = rsum[n];
        float bn = bias[n];
#pragma unroll
        for (int i = 0; i < 8; i++) {
            int mb = m0 + (wmi << 7) + i * 16 + lq * 4;
#pragma unroll
            for (int rg = 0; rg < 4; rg++) {
                int v = acc[i][j][rg] - zx * rsn;
                float fv = (float)v * s1 + bn;
                float g = fv * 0.5f * (1.0f + fast_erf(fv * 0.7071067811865476f));
                _Float16 gh = (_Float16)g;
                H[(long)(mb + rg) * D_HID + n] = gh;
                float gf = (float)gh;
                lmin = fminf(lmin, gf);
                lmax = fmaxf(lmax, gf);
            }
        }
    }
    for (int off = 32; off > 0; off >>= 1) {
        lmin = fminf(lmin, __shfl_down(lmin, off));
        lmax = fmaxf(lmax, __shfl_down(lmax, off));
    }
    __syncthreads();
    if (l == 0) { red[w] = lmin; red[4 + w] = lmax; }
    __syncthreads();
    if (tid == 0) {
        atomicMin(&slots[4], enc_f(fminf(fminf(red[0], red[1]), fminf(red[2], red[3]))));
        atomicMax(&slots[5], enc_f(fmaxf(fmaxf(red[4], red[5]), fmaxf(red[6], red[7]))));
    }
}

__global__ __launch_bounds__(256, 3) void k_gemm2(const signed char* __restrict__ Aq,
                                                  const signed char* __restrict__ Bq,
                                                  float* __restrict__ Out,
                                                  const float* __restrict__ scal,
                                                  const unsigned* __restrict__ slots,
                                                  const int* __restrict__ rsum,
                                                  const float* __restrict__ bias) {
    __shared__ __align__(16) signed char Ls[2 * 24576];
    const int nb = D_IN / 128;
    const int m0 = (blockIdx.x / nb) * 256, n0 = (blockIdx.x % nb) * 128;
    v4i acc[8][4];
    v4i zero = {0, 0, 0, 0};
#pragma unroll
    for (int i = 0; i < 8; i++)
#pragma unroll
        for (int j = 0; j < 4; j++) acc[i][j] = zero;
    int8_mainloop256(Aq, Bq, D_HID, m0, n0, Ls, acc);

    const int tid = threadIdx.x, l = tid & 63, w = tid >> 6;
    const int lm = l & 15, lq = l >> 4;
    const int wmi = w >> 1, wni = w & 1;
    // stage-2 scales decoded inline from slots (identical math to old k_scales2)
    float amin = dec_f(slots[4]), amax = dec_f(slots[5]);
    float sh = fmaxf((amax - amin) / 255.0f, 1e-8f);
    float zpf = rintf(-amin / sh) - 128.0f;
    zpf = fminf(fmaxf(zpf, -128.0f), 127.0f);
    float s2 = sh * scal[3];
    int zx = (int)zpf;
#pragma unroll
    for (int j = 0; j < 4; j++) {
        int n = n0 + (wni << 6) + j * 16 + lm;
        int rsn = rsum[n];
        float bn = bias[n];
#pragma unroll
        for (int i = 0; i < 8; i++) {
            int mb = m0 + (wmi << 7) + i * 16 + lq * 4;
#pragma unroll
            for (int rg = 0; rg < 4; rg++) {
                int v = acc[i][j][rg] - zx * rsn;
                Out[(long)(mb + rg) * D_IN + n] = (float)v * s2 + bn;
            }
        }
    }
}

extern "C" void kernel_launch(void* const* d_in, const int* in_sizes, int n_in,
                              void* d_out, int out_size, void* d_ws, size_t ws_size,
                              hipStream_t stream) {
    const float* x  = (const float*)d_in[0];
    const float* W1 = (const float*)d_in[1];
    const float* b1 = (const float*)d_in[2];
    const float* W2 = (const float*)d_in[3];
    const float* b2 = (const float*)d_in[4];

    char* ws = (char*)d_ws;
    unsigned* slots    = (unsigned*)(ws + OFF_SLOTS);
    float* scal        = (float*)(ws + OFF_SCAL);
    int* iscal         = (int*)(ws + OFF_ISCAL);
    signed char* xq    = (signed char*)(ws + OFF_XQ);
    signed char* w1q   = (signed char*)(ws + OFF_W1Q);
    signed char* w2q   = (signed char*)(ws + OFF_W2Q);
    int* rs1           = (int*)(ws + OFF_RS1);
    int* rs2           = (int*)(ws + OFF_RS2);
    _Float16* h        = (_Float16*)(ws + OFF_H);
    signed char* hq    = (signed char*)(ws + OFF_HQ);

    // reduction partials live in the (currently dead) RS1/RS2 regions:
    // kernel 1 writes them, kernel 2 reads them, kernel 3 overwrites with rsums.
    float* pxmin = (float*)(ws + OFF_RS1);          // 1024 f32
    float* pxmax = pxmin + 1024;                    // 1024 f32 (8KB <= 16KB)
    float* pw1   = (float*)(ws + OFF_RS2);          // 256 f32
    float* pw2   = pw1 + 256;                       // 256 f32 (2KB <= 4KB)

    k_reduce_all<<<1536, 256, 0, stream>>>((const float4*)x, (const float4*)W1,
                                           (const float4*)W2, pxmin, pxmax, pw1, pw2);
    k_scales_all<<<1, 64, 0, stream>>>(pxmin, pxmax, pw1, pw2, scal, iscal, slots);
    k_quant_all<<<7168, 256, 0, stream>>>((const float4*)x, (int*)xq,
                                          W1, w1q, rs1, W2, w2q, rs2, scal);
    k_gemm1<<<(M_TOK / 256) * (D_HID / 128), 256, 0, stream>>>(xq, w1q, h, scal, iscal, rs1, b1, slots);
    k_quant_h<<<4096, 256, 0, stream>>>((const f16x8*)h, (int2*)hq, M_TOK * D_HID / 8, slots);
    k_gemm2<<<(M_TOK / 256) * (D_IN / 128), 256, 0, stream>>>(hq, w2q, (float*)d_out, scal, slots, rs2, b2);
}

// Round 8
// 410.623 us; speedup vs baseline: 1.8180x; 1.8180x over previous
//
#include <hip/hip_runtime.h>
#include <hip/hip_bf16.h>
#include <math.h>

// Problem dims (fixed by reference setup_inputs)
#define D_IN   1024
#define D_HID  4096
#define M_TOK  16384   // 4 * 4096 tokens

typedef int v4i __attribute__((ext_vector_type(4)));
typedef _Float16 f16x8 __attribute__((ext_vector_type(8)));

typedef __attribute__((address_space(3))) unsigned int lds_u32;
typedef const __attribute__((address_space(1))) unsigned int glb_u32;

// async global->LDS, 16B per lane, wave-uniform LDS base + lane*16
__device__ inline void gload_lds16(const signed char* g, signed char* l) {
    __builtin_amdgcn_global_load_lds((glb_u32*)g, (lds_u32*)l, 16, 0, 0);
}

// Branchless erf, Abramowitz-Stegun 7.1.26, |eps| <= 1.5e-7 (<< fp16-h rounding).
__device__ inline float fast_erf(float x) {
    float ax = fabsf(x);
    float t = __builtin_amdgcn_rcpf(fmaf(0.3275911f, ax, 1.0f));
    float y = t * (0.254829592f +
              t * (-0.284496736f +
              t * (1.421413741f +
              t * (-1.453152027f +
              t * 1.061405429f))));
    float e = __expf(-ax * ax);          // native v_exp path
    float r = fmaf(-y, e, 1.0f);
    return copysignf(r, x);
}

// ---------------- workspace layout (bytes) ----------------
#define OFF_SLOTS  ((size_t)0)                                   // 8 x u32 atomic slots
#define OFF_SCAL   ((size_t)64)                                  // 16 x f32 scalars
#define OFF_ISCAL  ((size_t)128)                                 // 8 x i32
#define OFF_XQ     ((size_t)256)                                 // 16M  int8
#define OFF_W1Q    (OFF_XQ  + (size_t)M_TOK * D_IN)              // 4M   int8
#define OFF_W2Q    (OFF_W1Q + (size_t)D_HID * D_IN)              // 4M   int8
#define OFF_RS1    (OFF_W2Q + (size_t)D_IN * D_HID)              // 16K  i32
#define OFF_RS2    (OFF_RS1 + (size_t)D_HID * 4)                 // 4K   i32
#define OFF_H      (OFF_RS2 + (size_t)D_IN * 4 + 128)            // 128M fp16
#define OFF_HQ     (OFF_H   + (size_t)M_TOK * D_HID * 2)         // 64M  int8
// total ~226.5 MB
// Reduction partials (k_reduce_all -> k_quant_all) live at the head of the
// HQ region, which is dead until k_quant_h (strictly after k_quant_all in
// stream order). NOT in RS1/RS2: k_quant_all writes rsums there while other
// blocks still read partials (would race).

// slots: [4] h min(enc) [5] h max(enc)
// scal:  [0] sx1 [1] zx1f [2] sw1 [3] sw2 [4] s1=sx1*sw1   (written by quant_all blk 0)
// iscal: [0] zx1

__device__ inline unsigned enc_f(float f) {
    unsigned u = __float_as_uint(f);
    return (u & 0x80000000u) ? ~u : (u | 0x80000000u);
}
__device__ inline float dec_f(unsigned u) {
    return __uint_as_float((u & 0x80000000u) ? (u ^ 0x80000000u) : ~u);
}

// ---- fused stage-1 reductions: x min/max + |W1|max + |W2|max, deterministic partials
__global__ void k_reduce_all(const float4* __restrict__ x,
                             const float4* __restrict__ w1,
                             const float4* __restrict__ w2,
                             float* __restrict__ pxmin, float* __restrict__ pxmax,
                             float* __restrict__ pw1, float* __restrict__ pw2) {
    __shared__ float red[8];
    const int b = blockIdx.x;
    const int wave = threadIdx.x >> 6, lane = threadIdx.x & 63;
    if (b < 1024) {
        float vmin = 3.4e38f, vmax = -3.4e38f;
        for (int i = b * 256 + threadIdx.x; i < M_TOK * D_IN / 4; i += 1024 * 256) {
            float4 v = x[i];
            vmin = fminf(vmin, fminf(fminf(v.x, v.y), fminf(v.z, v.w)));
            vmax = fmaxf(vmax, fmaxf(fmaxf(v.x, v.y), fmaxf(v.z, v.w)));
        }
        for (int off = 32; off > 0; off >>= 1) {
            vmin = fminf(vmin, __shfl_down(vmin, off));
            vmax = fmaxf(vmax, __shfl_down(vmax, off));
        }
        if (lane == 0) { red[wave] = vmin; red[4 + wave] = vmax; }
        __syncthreads();
        if (threadIdx.x == 0) {
            pxmin[b] = fminf(fminf(red[0], red[1]), fminf(red[2], red[3]));
            pxmax[b] = fmaxf(fmaxf(red[4], red[5]), fmaxf(red[6], red[7]));
        }
    } else {
        const float4* w = (b < 1280) ? w1 : w2;
        const int bb = (b < 1280) ? b - 1024 : b - 1280;
        float vmax = 0.0f;
        for (int i = bb * 256 + threadIdx.x; i < D_HID * D_IN / 4; i += 256 * 256) {
            float4 v = w[i];
            vmax = fmaxf(vmax, fmaxf(fmaxf(fabsf(v.x), fabsf(v.y)), fmaxf(fabsf(v.z), fabsf(v.w))));
        }
        for (int off = 32; off > 0; off >>= 1)
            vmax = fmaxf(vmax, __shfl_down(vmax, off));
        if (lane == 0) red[wave] = vmax;
        __syncthreads();
        if (threadIdx.x == 0) {
            float bm = fmaxf(fmaxf(red[0], red[1]), fmaxf(red[2], red[3]));
            if (b < 1280) pw1[bb] = bm; else pw2[bb] = bm;
        }
    }
}

// ---- fused stage-1 quantization (k_scales_all folded in):
// x (blocks 0..2047), W1 rows (2048..6143), W2 rows (6144..7167).
// Each block locally reduces the partials it needs (L2-hot, few KB);
// block 0 additionally publishes scal/iscal/slots for gemm1/gemm2.
__global__ void k_quant_all(const float4* __restrict__ x, int* __restrict__ xq,
                            const float* __restrict__ W1, signed char* __restrict__ w1q,
                            int* __restrict__ rs1,
                            const float* __restrict__ W2, signed char* __restrict__ w2q,
                            int* __restrict__ rs2,
                            const float* __restrict__ pxmin, const float* __restrict__ pxmax,
                            const float* __restrict__ pw1, const float* __restrict__ pw2,
                            float* __restrict__ scal, int* __restrict__ iscal,
                            unsigned* __restrict__ slots) {
    __shared__ float sred[8];
    __shared__ int red[4];
    const int b = blockIdx.x;
    const int wave = threadIdx.x >> 6, lane = threadIdx.x & 63;

    if (b < 2048) {
        // local x-scale from partials (1024+1024 f32, L2-resident)
        float vmin = 3.4e38f, vmax = -3.4e38f;
        for (int i = threadIdx.x; i < 1024; i += 256) {
            vmin = fminf(vmin, pxmin[i]);
            vmax = fmaxf(vmax, pxmax[i]);
        }
        for (int off = 32; off > 0; off >>= 1) {
            vmin = fminf(vmin, __shfl_down(vmin, off));
            vmax = fmaxf(vmax, __shfl_down(vmax, off));
        }
        if (lane == 0) { sred[wave] = vmin; sred[4 + wave] = vmax; }
        __syncthreads();
        vmin = fminf(fminf(sred[0], sred[1]), fminf(sred[2], sred[3]));
        vmax = fmaxf(fmaxf(sred[4], sred[5]), fmaxf(sred[6], sred[7]));
        float s = fmaxf((vmax - vmin) / 255.0f, 1e-8f);
        float zp = rintf(-vmin / s) - 128.0f;
        zp = fminf(fmaxf(zp, -128.0f), 127.0f);

        if (b == 0 && threadIdx.x == 0) {
            float w1m = 0.0f, w2m = 0.0f;
            for (int i = 0; i < 256; i++) {
                w1m = fmaxf(w1m, pw1[i]);
                w2m = fmaxf(w2m, pw2[i]);
            }
            float sw1 = fmaxf(w1m / 127.0f, 1e-8f);
            float sw2 = fmaxf(w2m / 127.0f, 1e-8f);
            scal[0] = s; scal[1] = zp; scal[2] = sw1; scal[3] = sw2; scal[4] = s * sw1;
            iscal[0] = (int)zp;
            slots[4] = 0xFFFFFFFFu;   // h min (enc)
            slots[5] = 0u;            // h max (enc)
        }

        for (int i = b * 256 + threadIdx.x; i < M_TOK * D_IN / 4; i += 2048 * 256) {
            float4 v = x[i];
            int a0 = (int)fminf(fmaxf(rintf(v.x / s) + zp, -128.0f), 127.0f);
            int a1 = (int)fminf(fmaxf(rintf(v.y / s) + zp, -128.0f), 127.0f);
            int a2 = (int)fminf(fmaxf(rintf(v.z / s) + zp, -128.0f), 127.0f);
            int a3 = (int)fminf(fmaxf(rintf(v.w / s) + zp, -128.0f), 127.0f);
            xq[i] = (a0 & 255) | ((a1 & 255) << 8) | ((a2 & 255) << 16) | ((a3 & 255) << 24);
        }
        return;
    }

    const int isW1 = (b < 2048 + 4096);
    const int row = isW1 ? (b - 2048) : (b - 6144);
    const int K = isW1 ? D_IN : D_HID;
    const float* pw = isW1 ? pw1 : pw2;
    const float* W = isW1 ? W1 : W2;
    signed char* Wq = isW1 ? w1q : w2q;
    int* rsum = isW1 ? rs1 : rs2;

    // local weight-scale from the 256 partials
    float wm = pw[threadIdx.x & 255];
    for (int off = 32; off > 0; off >>= 1)
        wm = fmaxf(wm, __shfl_down(wm, off));
    if (lane == 0) sred[wave] = wm;
    __syncthreads();
    wm = fmaxf(fmaxf(sred[0], sred[1]), fmaxf(sred[2], sred[3]));
    const float s = fmaxf(wm / 127.0f, 1e-8f);

    const float4* Wr = (const float4*)(W + (size_t)row * K);
    int* out = (int*)(Wq + (size_t)row * K);
    int mysum = 0;
    for (int i = threadIdx.x; i < K / 4; i += 256) {
        float4 v = Wr[i];
        int a0 = (int)fminf(fmaxf(rintf(v.x / s), -127.0f), 127.0f);
        int a1 = (int)fminf(fmaxf(rintf(v.y / s), -127.0f), 127.0f);
        int a2 = (int)fminf(fmaxf(rintf(v.z / s), -127.0f), 127.0f);
        int a3 = (int)fminf(fmaxf(rintf(v.w / s), -127.0f), 127.0f);
        mysum += a0 + a1 + a2 + a3;
        out[i] = (a0 & 255) | ((a1 & 255) << 8) | ((a2 & 255) << 16) | ((a3 & 255) << 24);
    }
    for (int off = 32; off > 0; off >>= 1)
        mysum += __shfl_down(mysum, off);
    if (lane == 0) red[wave] = mysum;
    __syncthreads();
    if (threadIdx.x == 0) rsum[row] = red[0] + red[1] + red[2] + red[3];
}

// h quant: scales decoded inline from slots
__global__ void k_quant_h(const f16x8* __restrict__ H, int2* __restrict__ Hq, int n8,
                          const unsigned* __restrict__ slots) {
    float amin = dec_f(slots[4]), amax = dec_f(slots[5]);
    float s = fmaxf((amax - amin) / 255.0f, 1e-8f);
    float zp = rintf(-amin / s) - 128.0f;
    zp = fminf(fmaxf(zp, -128.0f), 127.0f);
    for (int i = blockIdx.x * blockDim.x + threadIdx.x; i < n8; i += gridDim.x * blockDim.x) {
        f16x8 v = H[i];
        int q[8];
#pragma unroll
        for (int j = 0; j < 8; j++)
            q[j] = ((int)fminf(fmaxf(rintf((float)v[j] / s) + zp, -128.0f), 127.0f)) & 255;
        int lo = q[0] | (q[1] << 8) | (q[2] << 16) | (q[3] << 24);
        int hi = q[4] | (q[5] << 8) | (q[6] << 16) | (q[7] << 24);
        Hq[i] = make_int2(lo, hi);
    }
}

// ---------------- int8 MFMA GEMM mainloop, 256x128 tile ----------------
// (R4-verified structure, untouched: triple-buffered 3x24KB LDS, prefetch
// depth 2, counted vmcnt(6) once per K-tile, 2 barriers/tile; see R2/R4
// safety argument. 2 blocks/CU; R6 proved 3 blocks/CU spills acc to scratch
// [VGPR pool 512/SIMD, kernel needs ~190/wave], R5 proved finer phases
// regress at 4 waves/block. This is the structural plateau for this family.)
__device__ inline void int8_mainloop256(const signed char* __restrict__ A,
                                        const signed char* __restrict__ B,
                                        int K, int m0, int n0,
                                        signed char* Ls, v4i (&acc)[8][4]) {
    const int tid = threadIdx.x;
    const int l = tid & 63, w = tid >> 6;
    const int lm = l & 15, lq = l >> 4;
    const int wmi = w >> 1, wni = w & 1;

    const int gc16 = ((l & 3) ^ ((l >> 3) & 3)) << 4;   // swizzled global chunk
    const int srow = (w << 4) + (l >> 2);               // rows 0..63 (+q*64)
    const signed char* gA = A + (long)(m0 + srow) * K + gc16;
    const signed char* gB = B + (long)(n0 + srow) * K + gc16;
    const long rstep = (long)K << 6;                    // 64 rows
    signed char* lA = Ls + (w << 10) + (l << 4);
    signed char* lB = Ls + 16384 + (w << 10) + (l << 4);

    const int f16off = (lq ^ ((lm >> 1) & 3)) << 4;
    const int aoff = ((wmi << 7) + lm) * 64 + f16off;
    const int boff = 16384 + ((wni << 6) + lm) * 64 + f16off;

    const int KT = K >> 6;

    auto stage = [&](int bufoff, int kt) {
        const signed char* a = gA + ((long)kt << 6);
        const signed char* b = gB + ((long)kt << 6);
        gload_lds16(a,             lA + bufoff);
        gload_lds16(a + rstep,     lA + bufoff + 4096);
        gload_lds16(a + 2 * rstep, lA + bufoff + 8192);
        gload_lds16(a + 3 * rstep, lA + bufoff + 12288);
        gload_lds16(b,             lB + bufoff);
        gload_lds16(b + rstep,     lB + bufoff + 4096);
    };

    auto compute = [&](int bufoff) {
        v4i av[8], bv[4];
#pragma unroll
        for (int j = 0; j < 4; ++j)
            bv[j] = *(const v4i*)&Ls[bufoff + boff + j * 1024];
#pragma unroll
        for (int i = 0; i < 8; ++i)
            av[i] = *(const v4i*)&Ls[bufoff + aoff + i * 1024];
        __builtin_amdgcn_s_setprio(1);
#pragma unroll
        for (int i = 0; i < 8; ++i)
#pragma unroll
            for (int j = 0; j < 4; ++j)
                acc[i][j] = __builtin_amdgcn_mfma_i32_16x16x64_i8(av[i], bv[j], acc[i][j], 0, 0, 0);
        __builtin_amdgcn_s_setprio(0);
    };

    stage(0, 0);
    stage(24576, 1);

    int b0 = 0, b1 = 24576, b2 = 49152;
    for (int t = 0; t < KT - 2; ++t) {
        asm volatile("s_waitcnt vmcnt(6)\n\ts_barrier" ::: "memory");
        stage(b2, t + 2);
        compute(b0);
        int tmp = b0; b0 = b1; b1 = b2; b2 = tmp;
    }
    asm volatile("s_waitcnt vmcnt(6)\n\ts_barrier" ::: "memory");
    compute(b0);
    asm volatile("s_waitcnt vmcnt(0)\n\ts_barrier" ::: "memory");
    compute(b1);
}

// T1: bijective XCD-chunked block swizzle (nwg % 8 == 0 for both GEMM grids).
// XCD k gets nwg/8 CONSECUTIVE logical tiles -> A-panel reuse lands in k's L2.
__device__ inline int xcd_swizzle(int b, int nwg) {
    const int cpx = nwg >> 3;
    return (b & 7) * cpx + (b >> 3);
}

__global__ __launch_bounds__(256, 2) void k_gemm1(const signed char* __restrict__ Aq,
                                                  const signed char* __restrict__ Bq,
                                                  _Float16* __restrict__ H,
                                                  const float* __restrict__ scal,
                                                  const int* __restrict__ iscal,
                                                  const int* __restrict__ rsum,
                                                  const float* __restrict__ bias,
                                                  unsigned* slots) {
    __shared__ __align__(16) signed char Ls[3 * 24576];   // 72KB -> 2 blocks/CU
    __shared__ float red[8];
    const int nb = D_HID / 128;
    const int bid = xcd_swizzle(blockIdx.x, (M_TOK / 256) * nb);
    const int m0 = (bid / nb) * 256, n0 = (bid % nb) * 128;
    v4i acc[8][4];
    v4i zero = {0, 0, 0, 0};
#pragma unroll
    for (int i = 0; i < 8; i++)
#pragma unroll
        for (int j = 0; j < 4; j++) acc[i][j] = zero;
    int8_mainloop256(Aq, Bq, D_IN, m0, n0, Ls, acc);

    const int tid = threadIdx.x, l = tid & 63, w = tid >> 6;
    const int lm = l & 15, lq = l >> 4;
    const int wmi = w >> 1, wni = w & 1;
    float s1 = scal[4];
    int zx = iscal[0];
    float lmin = 3.4e38f, lmax = -3.4e38f;

    // all waves done reading mainloop LDS before we overwrite it
    __syncthreads();

    // phase 1: GELU + ds_write_b16 into XOR-swizzled 256x128 fp16 tile (64KB).
    // swizzle off ^= ((row>>2)&7)<<5: bijective per row (xor touches col-byte
    // bits 5-7 only; col mapping on 16B blocks is identity after read-side XOR).
#pragma unroll
    for (int j = 0; j < 4; j++) {
        int n = n0 + (wni << 6) + j * 16 + lm;
        int rsn = rsum[n];
        float bn = bias[n];
        int colb = ((wni << 6) + j * 16 + lm) * 2;   // byte col in tile
#pragma unroll
        for (int i = 0; i < 8; i++) {
#pragma unroll
            for (int rg = 0; rg < 4; rg++) {
                int row = (wmi << 7) + i * 16 + lq * 4 + rg;
                int v = acc[i][j][rg] - zx * rsn;
                float fv = (float)v * s1 + bn;
                float g = fv * 0.5f * (1.0f + fast_erf(fv * 0.7071067811865476f));
                _Float16 gh = (_Float16)g;
                int off = (row * 256 + colb) ^ (((row >> 2) & 7) << 5);
                *(_Float16*)&Ls[off] = gh;
                float gf = (float)gh;
                lmin = fminf(lmin, gf);
                lmax = fmaxf(lmax, gf);
            }
        }
    }
    __syncthreads();

    // phase 2: coalesced store — 256 threads x 16B = 16 rows (256B each) per
    // iteration; 16 iterations cover all 256 tile rows.
#pragma unroll
    for (int it = 0; it < 16; it++) {
        int row = it * 16 + (tid >> 4);
        int c = tid & 15;
        int off = (row * 256 + c * 16) ^ (((row >> 2) & 7) << 5);
        v4i d = *(const v4i*)&Ls[off];
        *(v4i*)&H[(long)(m0 + row) * D_HID + n0 + c * 8] = d;
    }

    // block h-min/max -> global atomic slots
    for (int off = 32; off > 0; off >>= 1) {
        lmin = fminf(lmin, __shfl_down(lmin, off));
        lmax = fmaxf(lmax, __shfl_down(lmax, off));
    }
    if (l == 0) { red[w] = lmin; red[4 + w] = lmax; }
    __syncthreads();
    if (tid == 0) {
        atomicMin(&slots[4], enc_f(fminf(fminf(red[0], red[1]), fminf(red[2], red[3]))));
        atomicMax(&slots[5], enc_f(fmaxf(fmaxf(red[4], red[5]), fmaxf(red[6], red[7]))));
    }
}

__global__ __launch_bounds__(256, 2) void k_gemm2(const signed char* __restrict__ Aq,
                                                  const signed char* __restrict__ Bq,
                                                  float* __restrict__ Out,
                                                  const float* __restrict__ scal,
                                                  const unsigned* __restrict__ slots,
                                                  const int* __restrict__ rsum,
                                                  const float* __restrict__ bias) {
    __shared__ __align__(16) signed char Ls[3 * 24576];
    const int nb = D_IN / 128;
    const int bid = xcd_swizzle(blockIdx.x, (M_TOK / 256) * nb);
    const int m0 = (bid / nb) * 256, n0 = (bid % nb) * 128;
    v4i acc[8][4];
    v4i zero = {0, 0, 0, 0};
#pragma unroll
    for (int i = 0; i < 8; i++)
#pragma unroll
        for (int j = 0; j < 4; j++) acc[i][j] = zero;
    int8_mainloop256(Aq, Bq, D_HID, m0, n0, Ls, acc);

    const int tid = threadIdx.x, l = tid & 63, w = tid >> 6;
    const int lm = l & 15, lq = l >> 4;
    const int wmi = w >> 1, wni = w & 1;
    // stage-2 scales decoded inline from slots
    float amin = dec_f(slots[4]), amax = dec_f(slots[5]);
    float sh = fmaxf((amax - amin) / 255.0f, 1e-8f);
    float zpf = rintf(-amin / sh) - 128.0f;
    zpf = fminf(fmaxf(zpf, -128.0f), 127.0f);
    float s2 = sh * scal[3];
    int zx = (int)zpf;
#pragma unroll
    for (int j = 0; j < 4; j++) {
        int n = n0 + (wni << 6) + j * 16 + lm;
        int rsn = rsum[n];
        float bn = bias[n];
#pragma unroll
        for (int i = 0; i < 8; i++) {
            int mb = m0 + (wmi << 7) + i * 16 + lq * 4;
#pragma unroll
            for (int rg = 0; rg < 4; rg++) {
                int v = acc[i][j][rg] - zx * rsn;
                Out[(long)(mb + rg) * D_IN + n] = (float)v * s2 + bn;
            }
        }
    }
}

extern "C" void kernel_launch(void* const* d_in, const int* in_sizes, int n_in,
                              void* d_out, int out_size, void* d_ws, size_t ws_size,
                              hipStream_t stream) {
    const float* x  = (const float*)d_in[0];
    const float* W1 = (const float*)d_in[1];
    const float* b1 = (const float*)d_in[2];
    const float* W2 = (const float*)d_in[3];
    const float* b2 = (const float*)d_in[4];

    char* ws = (char*)d_ws;
    unsigned* slots    = (unsigned*)(ws + OFF_SLOTS);
    float* scal        = (float*)(ws + OFF_SCAL);
    int* iscal         = (int*)(ws + OFF_ISCAL);
    signed char* xq    = (signed char*)(ws + OFF_XQ);
    signed char* w1q   = (signed char*)(ws + OFF_W1Q);
    signed char* w2q   = (signed char*)(ws + OFF_W2Q);
    int* rs1           = (int*)(ws + OFF_RS1);
    int* rs2           = (int*)(ws + OFF_RS2);
    _Float16* h        = (_Float16*)(ws + OFF_H);
    signed char* hq    = (signed char*)(ws + OFF_HQ);

    // reduction partials at the head of the (dead-until-quant_h) HQ region:
    // written by k_reduce_all, read by k_quant_all, first overwritten by
    // k_quant_h — strictly later in stream order.
    float* pxmin = (float*)(ws + OFF_HQ);           // 1024 f32
    float* pxmax = pxmin + 1024;                    // 1024 f32
    float* pw1   = pxmax + 1024;                    // 256 f32
    float* pw2   = pw1 + 256;                       // 256 f32  (10KB total)

    k_reduce_all<<<1536, 256, 0, stream>>>((const float4*)x, (const float4*)W1,
                                           (const float4*)W2, pxmin, pxmax, pw1, pw2);
    k_quant_all<<<7168, 256, 0, stream>>>((const float4*)x, (int*)xq,
                                          W1, w1q, rs1, W2, w2q, rs2,
                                          pxmin, pxmax, pw1, pw2, scal, iscal, slots);
    k_gemm1<<<(M_TOK / 256) * (D_HID / 128), 256, 0, stream>>>(xq, w1q, h, scal, iscal, rs1, b1, slots);
    k_quant_h<<<4096, 256, 0, stream>>>((const f16x8*)h, (int2*)hq, M_TOK * D_HID / 8, slots);
    k_gemm2<<<(M_TOK / 256) * (D_IN / 128), 256, 0, stream>>>(hq, w2q, (float*)d_out, scal, slots, rs2, b2);
}